// Round 17
// baseline (281.080 us; speedup 1.0000x reference)
//
#include <hip/hip_runtime.h>

// ============================================================================
// Round 17: r16 + prep MLP hoist (structure frozen).
//   - KV section: both t-iterations' global loads issued into v[2][8] BEFORE
//     any LDS/kv stores (4 float4 in flight vs 2).
//   - Xcat section: 16 elems/thread (two independent float4-pairs in flight,
//     loads hoisted before stores); blocks cb*256 -> cb*128.
// GEMMs / softmax / tail / numerics identical to r16 -> absmax bit-identical.
// ============================================================================

#define BB 64
#define SS 512
#define HH 768
#define DWW 200

typedef __attribute__((ext_vector_type(8))) _Float16 f16x8;
typedef __attribute__((ext_vector_type(4))) _Float16 f16x4;
typedef __attribute__((ext_vector_type(4))) float f32x4;
typedef unsigned int u32;

__device__ __forceinline__ u32 fkey(float f) {
    u32 u = __float_as_uint(f);
    return (u & 0x80000000u) ? ~u : (u | 0x80000000u);
}
__device__ __forceinline__ float fdec(u32 k) {
    u32 u = (k & 0x80000000u) ? (k & 0x7fffffffu) : ~k;
    return __uint_as_float(u);
}
__device__ __forceinline__ f32x4 mm(f16x8 a, f16x8 b, f32x4 c) {
    return __builtin_amdgcn_mfma_f32_16x16x32_f16(a, b, c, 0, 0, 0);
}
__device__ __forceinline__ void gl16(const void* g, void* l) {
    __builtin_amdgcn_global_load_lds(
        (const __attribute__((address_space(1))) void*)g,
        (__attribute__((address_space(3))) void*)l, 16, 0, 0);
}

// ---------------------------------------------------------------------------
// k_setup: compaction scans only. [0,64) m1, [64,128) m2.
__global__ __launch_bounds__(64) void k_setup(
    const int* __restrict__ m1, const int* __restrict__ m2,
    int* __restrict__ idx1, int* __restrict__ rcnt1,
    int* __restrict__ idx2, int* __restrict__ rcnt2) {
    int bid = blockIdx.x, lane = threadIdx.x;
    int b = bid & 63;
    const int* m = (bid < 64) ? m1 : m2;
    int* idx = (bid < 64) ? idx1 : idx2;
    int* rcnt = (bid < 64) ? rcnt1 : rcnt2;
    int base = 0;
#pragma unroll
    for (int c = 0; c < 8; ++c) {
        int s = c * 64 + lane;
        int v = m[b * SS + s];
        unsigned long long bal = __ballot(v != 0);
        int pre = __popcll(bal & ((1ull << lane) - 1ull));
        if (v) idx[b * SS + base + pre] = s;
        base += __popcll(bal);
    }
    if (lane == 0) rcnt[b] = base;
}

// ---------------------------------------------------------------------------
// mega-prep (flat block decode):
//  [0, cb*128): KV 64x64 tiles, rows gathered via idx2, zero-padded to tpad2.
//  [cb*128, cb*256): compacted Xcat gather via idx1, 16 elems/thread.
//  +976 (first chunk only): 128 masks-out, 192 key-init, 600 Wb, 56 Ww.
__global__ __launch_bounds__(256) void k_prep(
    const float* __restrict__ x2, const float* __restrict__ tt2,
    const float* __restrict__ x1, const float* __restrict__ tt,
    const float* __restrict__ yv,
    const int* __restrict__ m1, const int* __restrict__ m2,
    const float* __restrict__ Wb, const float* __restrict__ Wwv,
    const int* __restrict__ idx1, const int* __restrict__ rcnt1,
    const int* __restrict__ idx2, const int* __restrict__ rcnt2,
    _Float16* __restrict__ kvB, _Float16* __restrict__ kvTB,
    _Float16* __restrict__ kvW, _Float16* __restrict__ kvTW,
    _Float16* __restrict__ XcB, _Float16* __restrict__ XcW,
    float* __restrict__ out, u32* __restrict__ k1, u32* __restrict__ k2,
    _Float16* __restrict__ wbTH, _Float16* __restrict__ wwTH,
    int cb, int b0) {
    __shared__ float tile[64][65];
    int bx = blockIdx.x, tid = threadIdx.x;
    int NKV = cb * 128, NXC = cb * 128;

    if (bx < NKV) {
        int cbi = bx >> 7, sub = bx & 127;
        int t0 = (sub & 7) * 64, ybr = sub >> 3;
        const float* src; _Float16* kv; _Float16* kvT; int D, DPAD, DTPAD, d0;
        if (ybr < 12) { src = x2;  kv = kvB; kvT = kvTB; D = 768; DPAD = 768; DTPAD = 768; d0 = ybr * 64; }
        else          { src = tt2; kv = kvW; kvT = kvTW; D = 200; DPAD = 256; DTPAD = 256; d0 = (ybr - 12) * 64; }
        int bg = b0 + cbi;
        int rc2 = rcnt2[bg];
        int tpad2 = (rc2 + 127) & ~127;
        if (t0 >= tpad2) return;
        int tq = tid >> 3, c8 = (tid & 7) * 8;
        int gd = d0 + c8;
        // ---- hoisted loads: both iterations before any stores ----
        float v[2][8];
#pragma unroll
        for (int i = 0; i < 2; ++i) {
#pragma unroll
            for (int j = 0; j < 8; ++j) v[i][j] = 0.f;
            int tg = t0 + tq + i * 32;
            if (tg < rc2) {
                int sg = idx2[bg * SS + tg];
                const float* rp = src + ((size_t)bg * SS + sg) * D + gd;
                if (gd + 7 < D) {
                    float4 p0 = *(const float4*)(rp);
                    float4 p1 = *(const float4*)(rp + 4);
                    v[i][0] = p0.x; v[i][1] = p0.y; v[i][2] = p0.z; v[i][3] = p0.w;
                    v[i][4] = p1.x; v[i][5] = p1.y; v[i][6] = p1.z; v[i][7] = p1.w;
                } else {
#pragma unroll
                    for (int j = 0; j < 8; ++j) {
                        int d = gd + j;
                        v[i][j] = (d < D) ? rp[j] : 0.f;
                    }
                }
            }
        }
        // ---- stores ----
#pragma unroll
        for (int i = 0; i < 2; ++i) {
            int t = tq + i * 32;
            f16x8 o;
#pragma unroll
            for (int j = 0; j < 8; ++j) {
                tile[t][c8 + j] = v[i][j];
                o[j] = (_Float16)v[i][j];
            }
            *(f16x8*)(kv + ((size_t)cbi * SS + t0 + t) * DPAD + gd) = o;
        }
        __syncthreads();
#pragma unroll
        for (int i = 0; i < 2; ++i) {
            int dl = tq + i * 32, gdr = d0 + dl;
            if (gdr < DTPAD) {
                f16x8 o;
#pragma unroll
                for (int j = 0; j < 8; ++j) o[j] = (_Float16)tile[c8 + j][dl];
                *(f16x8*)(kvT + ((size_t)cbi * DTPAD + gdr) * SS + t0 + c8) = o;
            }
        }
    } else if (bx < NKV + NXC) {
        int u = bx - NKV;
        int cbi = u >> 7, xb = u & 127;
        int bg = b0 + cbi;
        const float* X; _Float16* outp; int Din, KPAD; size_t ost;
        if (xb < 100) { X = x1; outp = XcB; Din = 768; KPAD = 800; ost = (size_t)cbi * 409600; }
        else { xb -= 100; X = tt; outp = XcW; Din = 200; KPAD = 224; ost = (size_t)cbi * 114688; }
        int i16 = (xb * 256 + tid) * 16;
        int s = i16 / KPAD, k0 = i16 - s * KPAD;
        int rc = rcnt1[bg];
        int rpad = (rc + 127) & ~127;
        if (s >= rpad) return;
        f16x8 o[2] = {};
        if (s < rc) {
            int sg = idx1[bg * SS + s];
            const float* Xr = X + ((size_t)bg * SS + sg) * Din;
            if (k0 + 15 < Din) {
                // hoisted: all 4 float4 loads before converts
                float4 p0 = *(const float4*)(Xr + k0);
                float4 p1 = *(const float4*)(Xr + k0 + 4);
                float4 p2 = *(const float4*)(Xr + k0 + 8);
                float4 p3 = *(const float4*)(Xr + k0 + 12);
                o[0][0] = (_Float16)p0.x; o[0][1] = (_Float16)p0.y;
                o[0][2] = (_Float16)p0.z; o[0][3] = (_Float16)p0.w;
                o[0][4] = (_Float16)p1.x; o[0][5] = (_Float16)p1.y;
                o[0][6] = (_Float16)p1.z; o[0][7] = (_Float16)p1.w;
                o[1][0] = (_Float16)p2.x; o[1][1] = (_Float16)p2.y;
                o[1][2] = (_Float16)p2.z; o[1][3] = (_Float16)p2.w;
                o[1][4] = (_Float16)p3.x; o[1][5] = (_Float16)p3.y;
                o[1][6] = (_Float16)p3.z; o[1][7] = (_Float16)p3.w;
            } else {
                float yval = yv[(size_t)bg * SS + sg];
#pragma unroll
                for (int q = 0; q < 2; ++q)
#pragma unroll
                    for (int e = 0; e < 8; ++e) {
                        int k = k0 + q * 8 + e;
                        float vv = (k < Din) ? Xr[k] : ((k == Din) ? yval : 0.f);
                        o[q][e] = (_Float16)vv;
                    }
            }
        }
        *(f16x8*)(outp + ost + (size_t)s * KPAD + k0) = o[0];
        *(f16x8*)(outp + ost + (size_t)s * KPAD + k0 + 8) = o[1];
    } else {
        int u = bx - NKV - NXC;
        if (u < 128) {
            int i = u * 256 + tid;
            out[BB + i]           = (float)(1 - m1[i]);
            out[BB + BB * SS + i] = (float)(1 - m2[i]);
        } else if (u < 320) {
            int i = (u - 128) * 256 + tid;
            u32 v = fkey(-1e5f);
            if (i < BB * HH) k1[i] = v;
            if (i < BB * DWW) k2[i] = v;
        } else if (u < 920) {
            int i = ((u - 320) * 256 + tid) * 4;   // < 768*800
            int n = i / 800, k = i - n * 800;
            f16x4 o;
#pragma unroll
            for (int j = 0; j < 4; ++j)
                o[j] = (_Float16)((k + j < 769) ? Wb[(size_t)(k + j) * 768 + n] : 0.f);
            *(f16x4*)(wbTH + i) = o;
        } else {
            int i = ((u - 920) * 256 + tid) * 4;   // < 256*224
            int n = i / 224, k = i - n * 224;
            f16x4 o;
#pragma unroll
            for (int j = 0; j < 4; ++j)
                o[j] = (_Float16)((k + j < 201 && n < 200) ? Wwv[(size_t)(k + j) * 200 + n] : 0.f);
            *(f16x4*)(wwTH + i) = o;
        }
    }
}

// ---------------------------------------------------------------------------
// Single-buffer 16KB GEMM core (8 blocks/CU). C[128x128] = A * B^T, BK=32.
// GN: exit N-tiles with n0 >= tpad2. RK: runtime K trip = (rc2+31)>>5.
// EPI=1: fp16 out via two-pass 64-row LDS-staged stores. EPI=2: fused
// normalize + row-gate + maxpool via atomicMax.
template<int KA, int KST, int TN, int SXW, int DV, int AS, int BS, int EPI,
         bool GN, bool RK>
__device__ __forceinline__ void mm_core(
    const _Float16* __restrict__ A, const _Float16* __restrict__ B,
    _Float16* __restrict__ O, const float* __restrict__ rsum,
    u32* __restrict__ keys, int jb, const int* __restrict__ rcnt1,
    const int* __restrict__ rcnt2, int b0, char* lds, float* rsv) {
    int cbi = jb / (4 * TN);
    int rest = jb - cbi * (4 * TN);
    int ts = rest / TN, tn = rest - ts * TN;
    int s0 = ts * 128, n0 = tn * 128;

    int rc = rcnt1[b0 + cbi];
    int rpad = (rc + 127) & ~127;
    if (s0 >= rpad) return;
    if constexpr (GN) {
        int tp2 = (rcnt2[b0 + cbi] + 127) & ~127;
        if (n0 >= tp2) return;
    }

    int tid = threadIdx.x, lane = tid & 63, wid = tid >> 6;
    int wr = wid >> 1, wc = wid & 1;
    int l15 = lane & 15, sl = lane >> 4, gb = sl * 4;

    const _Float16* srcA = A + (size_t)cbi * AS + (size_t)s0 * KA;
    const _Float16* srcB = B + (size_t)cbi * BS + (size_t)n0 * KA;

    if constexpr (EPI == 2) {
        if (tid < 128) rsv[tid] = rsum[cbi * SS + s0 + tid];
    }

    f32x4 zz = {0.f, 0.f, 0.f, 0.f};
    f32x4 acc[4][4];
#pragma unroll
    for (int i = 0; i < 4; ++i)
#pragma unroll
        for (int j = 0; j < 4; ++j) acc[i][j] = zz;

#define STAGE(ks)                                                             \
    _Pragma("unroll") for (int i = 0; i < 4; ++i) {                           \
        int c = wid + 4 * i;                                                  \
        int arr = c >> 3, sub = c & 7, slot = sub >> 1, rh = sub & 1;         \
        const _Float16* gp = (arr ? srcB : srcA) +                            \
            (size_t)(rh * 64 + lane) * KA + (ks) * 32 + slot * 8;             \
        gl16(gp, lds + c * 1024);                                             \
    }
#define KBODY(ks)                                                             \
    {                                                                         \
        STAGE(ks);                                                            \
        __syncthreads();                                                      \
        f16x8 a[4], b[4];                                                     \
        _Pragma("unroll") for (int mf = 0; mf < 4; ++mf)                      \
            a[mf] = *(const f16x8*)(lds + sl * 2048 +                         \
                                    (wr * 64 + mf * 16 + l15) * 16);          \
        _Pragma("unroll") for (int nf = 0; nf < 4; ++nf)                      \
            b[nf] = *(const f16x8*)(lds + 8192 + sl * 2048 +                  \
                                    (wc * 64 + nf * 16 + l15) * 16);          \
        _Pragma("unroll") for (int mf = 0; mf < 4; ++mf)                      \
            _Pragma("unroll") for (int nf = 0; nf < 4; ++nf)                  \
                acc[mf][nf] = mm(a[mf], b[nf], acc[mf][nf]);                  \
        __syncthreads();                                                      \
    }

    if constexpr (RK) {
        int kend = (rcnt2[b0 + cbi] + 31) >> 5;
        for (int ks = 0; ks < kend; ++ks) KBODY(ks);
    } else {
#pragma unroll
        for (int ks = 0; ks < KST; ++ks) KBODY(ks);
    }
#undef KBODY
#undef STAGE

    if constexpr (EPI == 1) {
        _Float16* ce = (_Float16*)lds;
#pragma unroll
        for (int half = 0; half < 2; ++half) {
            if (wr == half) {
#pragma unroll
                for (int mf = 0; mf < 4; ++mf)
#pragma unroll
                    for (int nf = 0; nf < 4; ++nf)
#pragma unroll
                        for (int r = 0; r < 4; ++r) {
                            int row = mf * 16 + gb + r;
                            int col = wc * 64 + nf * 16 + l15;
                            ce[row * 128 + col] = (_Float16)acc[mf][nf][r];
                        }
            }
            __syncthreads();
#pragma unroll
            for (int i = 0; i < 4; ++i) {
                int t = tid + i * 256;
                int row = t >> 4, col = (t & 15) * 8;
                *(f16x8*)(O + ((size_t)cbi * SS + s0 + half * 64 + row) * SXW +
                          n0 + col) = *(const f16x8*)(ce + row * 128 + col);
            }
            __syncthreads();
        }
    } else {
        int bg = b0 + cbi;
#pragma unroll
        for (int nf = 0; nf < 4; ++nf) {
            float mx = -3.0e38f;
#pragma unroll
            for (int mf = 0; mf < 4; ++mf)
#pragma unroll
                for (int r = 0; r < 4; ++r) {
                    int srow = wr * 64 + mf * 16 + gb + r;
                    if (s0 + srow < rc) mx = fmaxf(mx, acc[mf][nf][r] * rsv[srow]);
                }
            mx = fmaxf(mx, __shfl_xor(mx, 16));
            mx = fmaxf(mx, __shfl_xor(mx, 32));
            if (lane < 16) {
                int d = n0 + wc * 64 + nf * 16 + lane;
                if (d < DV) atomicMax(&keys[(size_t)bg * DV + d], fkey(mx));
            }
        }
    }
}

// Merged dual-instantiation GEMM, XCD-proportional branch split.
template<int EPI, bool GN, bool RK,
         int KA0, int KST0, int TN0, int SXW0, int DV0, int AS0, int BS0,
         int KA1, int KST1, int TN1, int SXW1, int DV1, int AS1, int BS1>
__global__ __launch_bounds__(256) void k_mmM(
    const _Float16* __restrict__ A0, const _Float16* __restrict__ B0,
    _Float16* __restrict__ O0, const float* __restrict__ rs0, u32* __restrict__ key0,
    const _Float16* __restrict__ A1, const _Float16* __restrict__ B1,
    _Float16* __restrict__ O1, const float* __restrict__ rs1, u32* __restrict__ key1,
    int nj0, const int* __restrict__ rcnt1, const int* __restrict__ rcnt2,
    int b0, int nwg) {
    __shared__ __align__(16) char lds[16384];
    __shared__ float rsv[128];
    int bid = blockIdx.x;
    int x = bid & 7, t = bid >> 3;
    int tb = nj0 >> 3;
    int tw = (nwg - nj0) >> 3;
    if (t < tb)
        mm_core<KA0, KST0, TN0, SXW0, DV0, AS0, BS0, EPI, GN, RK>(
            A0, B0, O0, rs0, key0, x * tb + t, rcnt1, rcnt2, b0, lds, rsv);
    else
        mm_core<KA1, KST1, TN1, SXW1, DV1, AS1, BS1, EPI, GN, RK>(
            A1, B1, O1, rs1, key1, x * tw + (t - tb), rcnt1, rcnt2, b0, lds, rsv);
}

// ---------------------------------------------------------------------------
// merged row softmax over fp16 S, IN-PLACE, column-compacted.
__global__ __launch_bounds__(256) void k_softmaxM(
    _Float16* __restrict__ SP0, float* __restrict__ rs0,
    _Float16* __restrict__ SP1, float* __restrict__ rs1,
    const int* __restrict__ rcnt1, const int* __restrict__ rcnt2,
    int nblk0, int b0) {
    int bid = blockIdx.x;
    bool selw = bid >= nblk0;
    int b = selw ? bid - nblk0 : bid;
    _Float16* SP = selw ? SP1 : SP0;
    float* rs = selw ? rs1 : rs0;
    int cbi = b >> 7, rb = b & 127;
    int wid = threadIdx.x >> 6, lane = threadIdx.x & 63;
    int row = rb * 4 + wid, bg = b0 + cbi;
    int rc1 = rcnt1[bg];
    if (row >= rc1) return;
    int rc2 = rcnt2[bg];
    int col0 = lane * 8;
    f16x8 sv = *(const f16x8*)(SP + ((size_t)cbi * SS + row) * SS + col0);
    float mx = -3.0e38f;
    float c[8];
#pragma unroll
    for (int j = 0; j < 8; ++j) {
        c[j] = (float)sv[j];
        if (col0 + j < rc2) mx = fmaxf(mx, c[j]);
    }
#pragma unroll
    for (int off = 1; off <= 32; off <<= 1) mx = fmaxf(mx, __shfl_xor(mx, off));
    f16x8 o;
    float sm = 0.f;
#pragma unroll
    for (int j = 0; j < 8; ++j) {
        _Float16 h = (col0 + j < rc2) ? (_Float16)__expf(c[j] - mx) : (_Float16)0.f;
        o[j] = h;
        sm += (float)h;
    }
#pragma unroll
    for (int off = 1; off <= 32; off <<= 1) sm += __shfl_xor(sm, off);
    *(f16x8*)(SP + ((size_t)cbi * SS + row) * SS + col0) = o;
    if (lane == 0) rs[cbi * SS + row] = 1.0f / sm;
}

// ---------------------------------------------------------------------------
// merged tail: per batch b, wvproj (200->768 via LDS) then final dot+sigmoid.
__global__ __launch_bounds__(256) void k_tail(
    const float* __restrict__ x1h, const float* __restrict__ x2h,
    const u32* __restrict__ keys, const u32* __restrict__ wvkeys,
    const float* __restrict__ Wp, const float* __restrict__ bp,
    const float* __restrict__ lw, const float* __restrict__ lb,
    float* __restrict__ out) {
    int b = blockIdx.x, tid = threadIdx.x;
    __shared__ float xv[DWW];
    __shared__ float wvp[HH];
    __shared__ float red[4];
    if (tid < DWW) xv[tid] = fdec(wvkeys[b * DWW + tid]);
    __syncthreads();
    for (int h = tid; h < HH; h += 256) {
        float acc = bp[h];
        for (int d = 0; d < DWW; ++d) acc += xv[d] * Wp[d * HH + h];
        wvp[h] = acc;
    }
    __syncthreads();
    float acc = 0.f;
    for (int i = tid; i < HH; i += 256) {
        acc += x1h[b * HH + i] * lw[i];
        acc += x2h[b * HH + i] * lw[HH + i];
        acc += fdec(keys[b * HH + i]) * lw[2 * HH + i];
        acc += wvp[i] * lw[3 * HH + i];
    }
    int wid = tid >> 6, lane = tid & 63;
#pragma unroll
    for (int off = 32; off; off >>= 1) acc += __shfl_down(acc, off);
    if (lane == 0) red[wid] = acc;
    __syncthreads();
    if (tid == 0) {
        float z = red[0] + red[1] + red[2] + red[3] + lb[0];
        out[b] = 1.f / (1.f + __expf(-z));
    }
}

// ---------------------------------------------------------------------------
extern "C" void kernel_launch(void* const* d_in, const int* in_sizes, int n_in,
                              void* d_out, int out_size, void* d_ws, size_t ws_size,
                              hipStream_t stream) {
    const float* x1   = (const float*)d_in[0];
    const float* x1h  = (const float*)d_in[1];
    const int*   m1   = (const int*)d_in[2];
    const float* y    = (const float*)d_in[3];
    const float* x2   = (const float*)d_in[4];
    const float* x2h  = (const float*)d_in[5];
    const int*   m2   = (const int*)d_in[6];
    const float* tt   = (const float*)d_in[7];
    const float* tt2  = (const float*)d_in[8];
    const float* Wb   = (const float*)d_in[9];
    const float* Wwv  = (const float*)d_in[10];
    const float* lwvw = (const float*)d_in[11];
    const float* lwvb = (const float*)d_in[12];
    const float* lw   = (const float*)d_in[13];
    const float* lb   = (const float*)d_in[14];
    float* out = (float*)d_out;
    char* ws = (char*)d_ws;

    // fixed region
    u32*      x12key   = (u32*)ws;                    // 196608
    u32*      x12wvkey = (u32*)(ws + 196608);         // 51200
    float*    rsumB    = (float*)(ws + 444416);       // 131072
    float*    rsumW    = (float*)(ws + 575488);       // 131072
    _Float16* wbTH     = (_Float16*)(ws + 706560);    // 768*800*2 = 1228800
    _Float16* wwTH     = (_Float16*)(ws + 1935360);   // 256*224*2 = 114688
    int*      idx1Buf  = (int*)(ws + 2050048);        // 131072
    int*      rcnt1Buf = (int*)(ws + 2181120);        // 256
    int*      idx2Buf  = (int*)(ws + 2181376);        // 131072
    int*      rcnt2Buf = (int*)(ws + 2312448);        // 256
    const size_t D0 = 2312704;

    k_setup<<<128, 64, 0, stream>>>(m1, m2, idx1Buf, rcnt1Buf, idx2Buf, rcnt2Buf);

    const size_t perb = 4194304;
    int nb = 1;
    if (ws_size > D0 + perb) nb = (int)((ws_size - D0) / perb);
    if (nb > BB) nb = BB;
    if (nb < 1) nb = 1;

    char* R = ws + D0;
    _Float16* XcB = (_Float16*)R;                            // stride 409600 elem
    _Float16* XcW = (_Float16*)(R + (size_t)nb * 819200);    // stride 114688 elem
    _Float16* S_b = (_Float16*)R;                            // stride 262144 elem (alias Xc; P in-place)
    _Float16* S_w = (_Float16*)(R + (size_t)nb * 524288);    // stride 262144 elem
    char* p = R + (size_t)nb * 1048576;
    _Float16* XW_b = (_Float16*)p; p += (size_t)nb * 786432;  // stride 393216 elem
    _Float16* XW_w = (_Float16*)p; p += (size_t)nb * 262144;  // stride 131072 elem
    _Float16* KV_b = (_Float16*)p; p += (size_t)nb * 786432;  // stride 393216 elem
    _Float16* KV_w = (_Float16*)p; p += (size_t)nb * 262144;  // stride 131072 elem
    _Float16* KT_b = (_Float16*)p; p += (size_t)nb * 786432;  // stride 393216 elem
    _Float16* KT_w = (_Float16*)p;                            // stride 131072 elem

    for (int b0 = 0; b0 < BB; b0 += nb) {
        int cb = (BB - b0 < nb) ? (BB - b0) : nb;
        int nprep = cb * 256 + ((b0 == 0) ? 976 : 0);
        k_prep<<<nprep, 256, 0, stream>>>(
            x2, tt2, x1, tt, y, m1, m2, Wb, Wwv,
            idx1Buf, rcnt1Buf, idx2Buf, rcnt2Buf,
            KV_b, KT_b, KV_w, KT_w, XcB, XcW,
            out, x12key, x12wvkey, wbTH, wwTH, cb, b0);
        // xw: bert KA=800,25 steps,TN=6,SXW=768; wv KA=224,7,TN=2,SXW=256
        k_mmM<1, false, false,
              800, 25, 6, 768, 0, 409600, 0,
              224,  7, 2, 256, 0, 114688, 0><<<cb * 32, 256, 0, stream>>>(
            XcB, wbTH, XW_b, nullptr, nullptr,
            XcW, wwTH, XW_w, nullptr, nullptr,
            cb * 24, rcnt1Buf, rcnt2Buf, b0, cb * 32);
        // scores -> fp16 S in place of Xc: N-gated at tpad2
        k_mmM<1, true, false,
              768, 24, 4, 512, 0, 393216, 393216,
              256,  8, 4, 512, 0, 131072, 131072><<<cb * 32, 256, 0, stream>>>(
            XW_b, KV_b, S_b, nullptr, nullptr,
            XW_w, KV_w, S_w, nullptr, nullptr,
            cb * 16, rcnt1Buf, rcnt2Buf, b0, cb * 32);
        k_softmaxM<<<cb * 256, 256, 0, stream>>>(
            S_b, rsumB, S_w, rsumW, rcnt1Buf, rcnt2Buf, cb * 128, b0);
        // pv: runtime K trip = (rc2+31)>>5; bert TN=6 DV=768; wv TN=2 DV=200
        k_mmM<2, false, true,
              512, 16, 6, 0, 768, 262144, 393216,
              512, 16, 2, 0, 200, 262144, 131072><<<cb * 32, 256, 0, stream>>>(
            S_b, KT_b, nullptr, rsumB, x12key,
            S_w, KT_w, nullptr, rsumW, x12wvkey,
            cb * 24, rcnt1Buf, rcnt2Buf, b0, cb * 32);
    }

    k_tail<<<BB, 256, 0, stream>>>(x1h, x2h, x12key, x12wvkey,
                                   lwvw, lwvb, lw, lb, out);
}

// Round 18
// 268.478 us; speedup vs baseline: 1.0469x; 1.0469x over previous
//
#include <hip/hip_runtime.h>

// ============================================================================
// Round 18: REVERT to round-16 kernel (best measured: 268.5 us).
//   r17's prep rewrite (MLP hoist + 16-elem Xcat, fewer blocks) regressed
//   77.5 -> 91 us: block-level parallelism, not per-thread MLP, hides latency
//   in the prep regime (third failed prep rewrite; r11/r16 shape is optimal).
// Pipeline: compaction scans -> mega-prep (KV col-compacted + Xcat row-
// compacted + setup sections) -> xw GEMM -> scores GEMM (fp16 S, N-gated) ->
// in-place softmax -> PV GEMM (runtime K, fused normalize+rowgate+maxpool)
// -> tail (wvproj + final dot + sigmoid).
// ============================================================================

#define BB 64
#define SS 512
#define HH 768
#define DWW 200

typedef __attribute__((ext_vector_type(8))) _Float16 f16x8;
typedef __attribute__((ext_vector_type(4))) _Float16 f16x4;
typedef __attribute__((ext_vector_type(4))) float f32x4;
typedef unsigned int u32;

__device__ __forceinline__ u32 fkey(float f) {
    u32 u = __float_as_uint(f);
    return (u & 0x80000000u) ? ~u : (u | 0x80000000u);
}
__device__ __forceinline__ float fdec(u32 k) {
    u32 u = (k & 0x80000000u) ? (k & 0x7fffffffu) : ~k;
    return __uint_as_float(u);
}
__device__ __forceinline__ f32x4 mm(f16x8 a, f16x8 b, f32x4 c) {
    return __builtin_amdgcn_mfma_f32_16x16x32_f16(a, b, c, 0, 0, 0);
}
__device__ __forceinline__ void gl16(const void* g, void* l) {
    __builtin_amdgcn_global_load_lds(
        (const __attribute__((address_space(1))) void*)g,
        (__attribute__((address_space(3))) void*)l, 16, 0, 0);
}

// ---------------------------------------------------------------------------
// k_setup: compaction scans only. [0,64) m1, [64,128) m2.
__global__ __launch_bounds__(64) void k_setup(
    const int* __restrict__ m1, const int* __restrict__ m2,
    int* __restrict__ idx1, int* __restrict__ rcnt1,
    int* __restrict__ idx2, int* __restrict__ rcnt2) {
    int bid = blockIdx.x, lane = threadIdx.x;
    int b = bid & 63;
    const int* m = (bid < 64) ? m1 : m2;
    int* idx = (bid < 64) ? idx1 : idx2;
    int* rcnt = (bid < 64) ? rcnt1 : rcnt2;
    int base = 0;
#pragma unroll
    for (int c = 0; c < 8; ++c) {
        int s = c * 64 + lane;
        int v = m[b * SS + s];
        unsigned long long bal = __ballot(v != 0);
        int pre = __popcll(bal & ((1ull << lane) - 1ull));
        if (v) idx[b * SS + base + pre] = s;
        base += __popcll(bal);
    }
    if (lane == 0) rcnt[b] = base;
}

// ---------------------------------------------------------------------------
// mega-prep (flat block decode):
//  [0, cb*128): KV 64x64 tiles, rows gathered via idx2, zero-padded to tpad2.
//  [cb*128, cb*384): compacted Xcat gather via idx1.
//  +976 (first chunk only): 128 masks-out, 192 key-init, 600 Wb, 56 Ww.
__global__ __launch_bounds__(256) void k_prep(
    const float* __restrict__ x2, const float* __restrict__ tt2,
    const float* __restrict__ x1, const float* __restrict__ tt,
    const float* __restrict__ yv,
    const int* __restrict__ m1, const int* __restrict__ m2,
    const float* __restrict__ Wb, const float* __restrict__ Wwv,
    const int* __restrict__ idx1, const int* __restrict__ rcnt1,
    const int* __restrict__ idx2, const int* __restrict__ rcnt2,
    _Float16* __restrict__ kvB, _Float16* __restrict__ kvTB,
    _Float16* __restrict__ kvW, _Float16* __restrict__ kvTW,
    _Float16* __restrict__ XcB, _Float16* __restrict__ XcW,
    float* __restrict__ out, u32* __restrict__ k1, u32* __restrict__ k2,
    _Float16* __restrict__ wbTH, _Float16* __restrict__ wwTH,
    int cb, int b0) {
    __shared__ float tile[64][65];
    int bx = blockIdx.x, tid = threadIdx.x;
    int NKV = cb * 128, NXC = cb * 256;

    if (bx < NKV) {
        int cbi = bx >> 7, sub = bx & 127;
        int t0 = (sub & 7) * 64, ybr = sub >> 3;
        const float* src; _Float16* kv; _Float16* kvT; int D, DPAD, DTPAD, d0;
        if (ybr < 12) { src = x2;  kv = kvB; kvT = kvTB; D = 768; DPAD = 768; DTPAD = 768; d0 = ybr * 64; }
        else          { src = tt2; kv = kvW; kvT = kvTW; D = 200; DPAD = 256; DTPAD = 256; d0 = (ybr - 12) * 64; }
        int bg = b0 + cbi;
        int rc2 = rcnt2[bg];
        int tpad2 = (rc2 + 127) & ~127;
        if (t0 >= tpad2) return;
        int tq = tid >> 3, c8 = (tid & 7) * 8;
#pragma unroll
        for (int i = 0; i < 2; ++i) {
            int t = tq + i * 32;
            int tg = t0 + t;
            int gd = d0 + c8;
            float v[8] = {0.f, 0.f, 0.f, 0.f, 0.f, 0.f, 0.f, 0.f};
            if (tg < rc2) {
                int sg = idx2[bg * SS + tg];
                const float* rp = src + ((size_t)bg * SS + sg) * D + gd;
                if (gd + 7 < D) {
                    float4 p0 = *(const float4*)(rp);
                    float4 p1 = *(const float4*)(rp + 4);
                    v[0] = p0.x; v[1] = p0.y; v[2] = p0.z; v[3] = p0.w;
                    v[4] = p1.x; v[5] = p1.y; v[6] = p1.z; v[7] = p1.w;
                } else {
#pragma unroll
                    for (int j = 0; j < 8; ++j) {
                        int d = gd + j;
                        v[j] = (d < D) ? src[((size_t)bg * SS + sg) * D + d] : 0.f;
                    }
                }
            }
            f16x8 o;
#pragma unroll
            for (int j = 0; j < 8; ++j) {
                tile[t][c8 + j] = v[j];
                o[j] = (_Float16)v[j];
            }
            *(f16x8*)(kv + ((size_t)cbi * SS + tg) * DPAD + gd) = o;
        }
        __syncthreads();
#pragma unroll
        for (int i = 0; i < 2; ++i) {
            int dl = tq + i * 32, gdr = d0 + dl;
            if (gdr < DTPAD) {
                f16x8 o;
#pragma unroll
                for (int j = 0; j < 8; ++j) o[j] = (_Float16)tile[c8 + j][dl];
                *(f16x8*)(kvT + ((size_t)cbi * DTPAD + gdr) * SS + t0 + c8) = o;
            }
        }
    } else if (bx < NKV + NXC) {
        int u = bx - NKV;
        int cbi = u >> 8, xb = u & 255;
        int bg = b0 + cbi;
        const float* X; _Float16* outp; int Din, KPAD; size_t ost;
        if (xb < 200) { X = x1; outp = XcB; Din = 768; KPAD = 800; ost = (size_t)cbi * 409600; }
        else { xb -= 200; X = tt; outp = XcW; Din = 200; KPAD = 224; ost = (size_t)cbi * 114688; }
        int i8 = (xb * 256 + tid) * 8;
        int s = i8 / KPAD, k0 = i8 - s * KPAD;
        int rc = rcnt1[bg];
        int rpad = (rc + 127) & ~127;
        if (s >= rpad) return;
        f16x8 o = {};
        if (s < rc) {
            int sg = idx1[bg * SS + s];
            const float* Xr = X + ((size_t)bg * SS + sg) * Din;
            if (k0 + 7 < Din) {
                float4 p0 = *(const float4*)(Xr + k0);
                float4 p1 = *(const float4*)(Xr + k0 + 4);
                o[0] = (_Float16)p0.x; o[1] = (_Float16)p0.y;
                o[2] = (_Float16)p0.z; o[3] = (_Float16)p0.w;
                o[4] = (_Float16)p1.x; o[5] = (_Float16)p1.y;
                o[6] = (_Float16)p1.z; o[7] = (_Float16)p1.w;
            } else {
#pragma unroll
                for (int j = 0; j < 8; ++j) {
                    int k = k0 + j;
                    float v = (k < Din) ? Xr[k]
                                        : ((k == Din) ? yv[(size_t)bg * SS + sg] : 0.f);
                    o[j] = (_Float16)v;
                }
            }
        }
        *(f16x8*)(outp + ost + (size_t)s * KPAD + k0) = o;
    } else {
        int u = bx - NKV - NXC;
        if (u < 128) {
            int i = u * 256 + tid;
            out[BB + i]           = (float)(1 - m1[i]);
            out[BB + BB * SS + i] = (float)(1 - m2[i]);
        } else if (u < 320) {
            int i = (u - 128) * 256 + tid;
            u32 v = fkey(-1e5f);
            if (i < BB * HH) k1[i] = v;
            if (i < BB * DWW) k2[i] = v;
        } else if (u < 920) {
            int i = ((u - 320) * 256 + tid) * 4;   // < 768*800
            int n = i / 800, k = i - n * 800;
            f16x4 o;
#pragma unroll
            for (int j = 0; j < 4; ++j)
                o[j] = (_Float16)((k + j < 769) ? Wb[(size_t)(k + j) * 768 + n] : 0.f);
            *(f16x4*)(wbTH + i) = o;
        } else {
            int i = ((u - 920) * 256 + tid) * 4;   // < 256*224
            int n = i / 224, k = i - n * 224;
            f16x4 o;
#pragma unroll
            for (int j = 0; j < 4; ++j)
                o[j] = (_Float16)((k + j < 201 && n < 200) ? Wwv[(size_t)(k + j) * 200 + n] : 0.f);
            *(f16x4*)(wwTH + i) = o;
        }
    }
}

// ---------------------------------------------------------------------------
// Single-buffer 16KB GEMM core (8 blocks/CU). C[128x128] = A * B^T, BK=32.
// GN: exit N-tiles with n0 >= tpad2. RK: runtime K trip = (rc2+31)>>5.
// EPI=1: fp16 out via two-pass 64-row LDS-staged stores. EPI=2: fused
// normalize + row-gate + maxpool via atomicMax.
template<int KA, int KST, int TN, int SXW, int DV, int AS, int BS, int EPI,
         bool GN, bool RK>
__device__ __forceinline__ void mm_core(
    const _Float16* __restrict__ A, const _Float16* __restrict__ B,
    _Float16* __restrict__ O, const float* __restrict__ rsum,
    u32* __restrict__ keys, int jb, const int* __restrict__ rcnt1,
    const int* __restrict__ rcnt2, int b0, char* lds, float* rsv) {
    int cbi = jb / (4 * TN);
    int rest = jb - cbi * (4 * TN);
    int ts = rest / TN, tn = rest - ts * TN;
    int s0 = ts * 128, n0 = tn * 128;

    int rc = rcnt1[b0 + cbi];
    int rpad = (rc + 127) & ~127;
    if (s0 >= rpad) return;
    if constexpr (GN) {
        int tp2 = (rcnt2[b0 + cbi] + 127) & ~127;
        if (n0 >= tp2) return;
    }

    int tid = threadIdx.x, lane = tid & 63, wid = tid >> 6;
    int wr = wid >> 1, wc = wid & 1;
    int l15 = lane & 15, sl = lane >> 4, gb = sl * 4;

    const _Float16* srcA = A + (size_t)cbi * AS + (size_t)s0 * KA;
    const _Float16* srcB = B + (size_t)cbi * BS + (size_t)n0 * KA;

    if constexpr (EPI == 2) {
        if (tid < 128) rsv[tid] = rsum[cbi * SS + s0 + tid];
    }

    f32x4 zz = {0.f, 0.f, 0.f, 0.f};
    f32x4 acc[4][4];
#pragma unroll
    for (int i = 0; i < 4; ++i)
#pragma unroll
        for (int j = 0; j < 4; ++j) acc[i][j] = zz;

#define STAGE(ks)                                                             \
    _Pragma("unroll") for (int i = 0; i < 4; ++i) {                           \
        int c = wid + 4 * i;                                                  \
        int arr = c >> 3, sub = c & 7, slot = sub >> 1, rh = sub & 1;         \
        const _Float16* gp = (arr ? srcB : srcA) +                            \
            (size_t)(rh * 64 + lane) * KA + (ks) * 32 + slot * 8;             \
        gl16(gp, lds + c * 1024);                                             \
    }
#define KBODY(ks)                                                             \
    {                                                                         \
        STAGE(ks);                                                            \
        __syncthreads();                                                      \
        f16x8 a[4], b[4];                                                     \
        _Pragma("unroll") for (int mf = 0; mf < 4; ++mf)                      \
            a[mf] = *(const f16x8*)(lds + sl * 2048 +                         \
                                    (wr * 64 + mf * 16 + l15) * 16);          \
        _Pragma("unroll") for (int nf = 0; nf < 4; ++nf)                      \
            b[nf] = *(const f16x8*)(lds + 8192 + sl * 2048 +                  \
                                    (wc * 64 + nf * 16 + l15) * 16);          \
        _Pragma("unroll") for (int mf = 0; mf < 4; ++mf)                      \
            _Pragma("unroll") for (int nf = 0; nf < 4; ++nf)                  \
                acc[mf][nf] = mm(a[mf], b[nf], acc[mf][nf]);                  \
        __syncthreads();                                                      \
    }

    if constexpr (RK) {
        int kend = (rcnt2[b0 + cbi] + 31) >> 5;
        for (int ks = 0; ks < kend; ++ks) KBODY(ks);
    } else {
#pragma unroll
        for (int ks = 0; ks < KST; ++ks) KBODY(ks);
    }
#undef KBODY
#undef STAGE

    if constexpr (EPI == 1) {
        // two-pass epilogue: 64 rows per pass through 16KB LDS.
        _Float16* ce = (_Float16*)lds;
#pragma unroll
        for (int half = 0; half < 2; ++half) {
            if (wr == half) {
#pragma unroll
                for (int mf = 0; mf < 4; ++mf)
#pragma unroll
                    for (int nf = 0; nf < 4; ++nf)
#pragma unroll
                        for (int r = 0; r < 4; ++r) {
                            int row = mf * 16 + gb + r;
                            int col = wc * 64 + nf * 16 + l15;
                            ce[row * 128 + col] = (_Float16)acc[mf][nf][r];
                        }
            }
            __syncthreads();
#pragma unroll
            for (int i = 0; i < 4; ++i) {
                int t = tid + i * 256;              // 1024 chunks of 8 f16
                int row = t >> 4, col = (t & 15) * 8;
                *(f16x8*)(O + ((size_t)cbi * SS + s0 + half * 64 + row) * SXW +
                          n0 + col) = *(const f16x8*)(ce + row * 128 + col);
            }
            __syncthreads();
        }
    } else {
        int bg = b0 + cbi;
#pragma unroll
        for (int nf = 0; nf < 4; ++nf) {
            float mx = -3.0e38f;
#pragma unroll
            for (int mf = 0; mf < 4; ++mf)
#pragma unroll
                for (int r = 0; r < 4; ++r) {
                    int srow = wr * 64 + mf * 16 + gb + r;
                    if (s0 + srow < rc) mx = fmaxf(mx, acc[mf][nf][r] * rsv[srow]);
                }
            mx = fmaxf(mx, __shfl_xor(mx, 16));
            mx = fmaxf(mx, __shfl_xor(mx, 32));
            if (lane < 16) {
                int d = n0 + wc * 64 + nf * 16 + lane;
                if (d < DV) atomicMax(&keys[(size_t)bg * DV + d], fkey(mx));
            }
        }
    }
}

// Merged dual-instantiation GEMM, XCD-proportional branch split.
template<int EPI, bool GN, bool RK,
         int KA0, int KST0, int TN0, int SXW0, int DV0, int AS0, int BS0,
         int KA1, int KST1, int TN1, int SXW1, int DV1, int AS1, int BS1>
__global__ __launch_bounds__(256) void k_mmM(
    const _Float16* __restrict__ A0, const _Float16* __restrict__ B0,
    _Float16* __restrict__ O0, const float* __restrict__ rs0, u32* __restrict__ key0,
    const _Float16* __restrict__ A1, const _Float16* __restrict__ B1,
    _Float16* __restrict__ O1, const float* __restrict__ rs1, u32* __restrict__ key1,
    int nj0, const int* __restrict__ rcnt1, const int* __restrict__ rcnt2,
    int b0, int nwg) {
    __shared__ __align__(16) char lds[16384];
    __shared__ float rsv[128];
    int bid = blockIdx.x;
    int x = bid & 7, t = bid >> 3;
    int tb = nj0 >> 3;
    int tw = (nwg - nj0) >> 3;
    if (t < tb)
        mm_core<KA0, KST0, TN0, SXW0, DV0, AS0, BS0, EPI, GN, RK>(
            A0, B0, O0, rs0, key0, x * tb + t, rcnt1, rcnt2, b0, lds, rsv);
    else
        mm_core<KA1, KST1, TN1, SXW1, DV1, AS1, BS1, EPI, GN, RK>(
            A1, B1, O1, rs1, key1, x * tw + (t - tb), rcnt1, rcnt2, b0, lds, rsv);
}

// ---------------------------------------------------------------------------
// merged row softmax over fp16 S, IN-PLACE, column-compacted.
__global__ __launch_bounds__(256) void k_softmaxM(
    _Float16* __restrict__ SP0, float* __restrict__ rs0,
    _Float16* __restrict__ SP1, float* __restrict__ rs1,
    const int* __restrict__ rcnt1, const int* __restrict__ rcnt2,
    int nblk0, int b0) {
    int bid = blockIdx.x;
    bool selw = bid >= nblk0;
    int b = selw ? bid - nblk0 : bid;
    _Float16* SP = selw ? SP1 : SP0;
    float* rs = selw ? rs1 : rs0;
    int cbi = b >> 7, rb = b & 127;
    int wid = threadIdx.x >> 6, lane = threadIdx.x & 63;
    int row = rb * 4 + wid, bg = b0 + cbi;
    int rc1 = rcnt1[bg];
    if (row >= rc1) return;
    int rc2 = rcnt2[bg];
    int col0 = lane * 8;
    f16x8 sv = *(const f16x8*)(SP + ((size_t)cbi * SS + row) * SS + col0);
    float mx = -3.0e38f;
    float c[8];
#pragma unroll
    for (int j = 0; j < 8; ++j) {
        c[j] = (float)sv[j];
        if (col0 + j < rc2) mx = fmaxf(mx, c[j]);
    }
#pragma unroll
    for (int off = 1; off <= 32; off <<= 1) mx = fmaxf(mx, __shfl_xor(mx, off));
    f16x8 o;
    float sm = 0.f;
#pragma unroll
    for (int j = 0; j < 8; ++j) {
        _Float16 h = (col0 + j < rc2) ? (_Float16)__expf(c[j] - mx) : (_Float16)0.f;
        o[j] = h;
        sm += (float)h;
    }
#pragma unroll
    for (int off = 1; off <= 32; off <<= 1) sm += __shfl_xor(sm, off);
    *(f16x8*)(SP + ((size_t)cbi * SS + row) * SS + col0) = o;
    if (lane == 0) rs[cbi * SS + row] = 1.0f / sm;
}

// ---------------------------------------------------------------------------
// merged tail: per batch b, wvproj (200->768 via LDS) then final dot+sigmoid.
__global__ __launch_bounds__(256) void k_tail(
    const float* __restrict__ x1h, const float* __restrict__ x2h,
    const u32* __restrict__ keys, const u32* __restrict__ wvkeys,
    const float* __restrict__ Wp, const float* __restrict__ bp,
    const float* __restrict__ lw, const float* __restrict__ lb,
    float* __restrict__ out) {
    int b = blockIdx.x, tid = threadIdx.x;
    __shared__ float xv[DWW];
    __shared__ float wvp[HH];
    __shared__ float red[4];
    if (tid < DWW) xv[tid] = fdec(wvkeys[b * DWW + tid]);
    __syncthreads();
    for (int h = tid; h < HH; h += 256) {
        float acc = bp[h];
        for (int d = 0; d < DWW; ++d) acc += xv[d] * Wp[d * HH + h];
        wvp[h] = acc;
    }
    __syncthreads();
    float acc = 0.f;
    for (int i = tid; i < HH; i += 256) {
        acc += x1h[b * HH + i] * lw[i];
        acc += x2h[b * HH + i] * lw[HH + i];
        acc += fdec(keys[b * HH + i]) * lw[2 * HH + i];
        acc += wvp[i] * lw[3 * HH + i];
    }
    int wid = tid >> 6, lane = tid & 63;
#pragma unroll
    for (int off = 32; off; off >>= 1) acc += __shfl_down(acc, off);
    if (lane == 0) red[wid] = acc;
    __syncthreads();
    if (tid == 0) {
        float z = red[0] + red[1] + red[2] + red[3] + lb[0];
        out[b] = 1.f / (1.f + __expf(-z));
    }
}

// ---------------------------------------------------------------------------
extern "C" void kernel_launch(void* const* d_in, const int* in_sizes, int n_in,
                              void* d_out, int out_size, void* d_ws, size_t ws_size,
                              hipStream_t stream) {
    const float* x1   = (const float*)d_in[0];
    const float* x1h  = (const float*)d_in[1];
    const int*   m1   = (const int*)d_in[2];
    const float* y    = (const float*)d_in[3];
    const float* x2   = (const float*)d_in[4];
    const float* x2h  = (const float*)d_in[5];
    const int*   m2   = (const int*)d_in[6];
    const float* tt   = (const float*)d_in[7];
    const float* tt2  = (const float*)d_in[8];
    const float* Wb   = (const float*)d_in[9];
    const float* Wwv  = (const float*)d_in[10];
    const float* lwvw = (const float*)d_in[11];
    const float* lwvb = (const float*)d_in[12];
    const float* lw   = (const float*)d_in[13];
    const float* lb   = (const float*)d_in[14];
    float* out = (float*)d_out;
    char* ws = (char*)d_ws;

    // fixed region
    u32*      x12key   = (u32*)ws;                    // 196608
    u32*      x12wvkey = (u32*)(ws + 196608);         // 51200
    float*    rsumB    = (float*)(ws + 444416);       // 131072
    float*    rsumW    = (float*)(ws + 575488);       // 131072
    _Float16* wbTH     = (_Float16*)(ws + 706560);    // 768*800*2 = 1228800
    _Float16* wwTH     = (_Float16*)(ws + 1935360);   // 256*224*2 = 114688
    int*      idx1Buf  = (int*)(ws + 2050048);        // 131072
    int*      rcnt1Buf = (int*)(ws + 2181120);        // 256
    int*      idx2Buf  = (int*)(ws + 2181376);        // 131072
    int*      rcnt2Buf = (int*)(ws + 2312448);        // 256
    const size_t D0 = 2312704;

    k_setup<<<128, 64, 0, stream>>>(m1, m2, idx1Buf, rcnt1Buf, idx2Buf, rcnt2Buf);

    const size_t perb = 4194304;
    int nb = 1;
    if (ws_size > D0 + perb) nb = (int)((ws_size - D0) / perb);
    if (nb > BB) nb = BB;
    if (nb < 1) nb = 1;

    char* R = ws + D0;
    _Float16* XcB = (_Float16*)R;                            // stride 409600 elem
    _Float16* XcW = (_Float16*)(R + (size_t)nb * 819200);    // stride 114688 elem
    _Float16* S_b = (_Float16*)R;                            // stride 262144 elem (alias Xc; P in-place)
    _Float16* S_w = (_Float16*)(R + (size_t)nb * 524288);    // stride 262144 elem
    char* p = R + (size_t)nb * 1048576;
    _Float16* XW_b = (_Float16*)p; p += (size_t)nb * 786432;  // stride 393216 elem
    _Float16* XW_w = (_Float16*)p; p += (size_t)nb * 262144;  // stride 131072 elem
    _Float16* KV_b = (_Float16*)p; p += (size_t)nb * 786432;  // stride 393216 elem
    _Float16* KV_w = (_Float16*)p; p += (size_t)nb * 262144;  // stride 131072 elem
    _Float16* KT_b = (_Float16*)p; p += (size_t)nb * 786432;  // stride 393216 elem
    _Float16* KT_w = (_Float16*)p;                            // stride 131072 elem

    for (int b0 = 0; b0 < BB; b0 += nb) {
        int cb = (BB - b0 < nb) ? (BB - b0) : nb;
        int nprep = cb * 384 + ((b0 == 0) ? 976 : 0);
        k_prep<<<nprep, 256, 0, stream>>>(
            x2, tt2, x1, tt, y, m1, m2, Wb, Wwv,
            idx1Buf, rcnt1Buf, idx2Buf, rcnt2Buf,
            KV_b, KT_b, KV_w, KT_w, XcB, XcW,
            out, x12key, x12wvkey, wbTH, wwTH, cb, b0);
        // xw: bert KA=800,25 steps,TN=6,SXW=768; wv KA=224,7,TN=2,SXW=256
        k_mmM<1, false, false,
              800, 25, 6, 768, 0, 409600, 0,
              224,  7, 2, 256, 0, 114688, 0><<<cb * 32, 256, 0, stream>>>(
            XcB, wbTH, XW_b, nullptr, nullptr,
            XcW, wwTH, XW_w, nullptr, nullptr,
            cb * 24, rcnt1Buf, rcnt2Buf, b0, cb * 32);
        // scores -> fp16 S in place of Xc: N-gated at tpad2
        k_mmM<1, true, false,
              768, 24, 4, 512, 0, 393216, 393216,
              256,  8, 4, 512, 0, 131072, 131072><<<cb * 32, 256, 0, stream>>>(
            XW_b, KV_b, S_b, nullptr, nullptr,
            XW_w, KV_w, S_w, nullptr, nullptr,
            cb * 16, rcnt1Buf, rcnt2Buf, b0, cb * 32);
        k_softmaxM<<<cb * 256, 256, 0, stream>>>(
            S_b, rsumB, S_w, rsumW, rcnt1Buf, rcnt2Buf, cb * 128, b0);
        // pv: runtime K trip = (rc2+31)>>5; bert TN=6 DV=768; wv TN=2 DV=200
        k_mmM<2, false, true,
              512, 16, 6, 0, 768, 262144, 393216,
              512, 16, 2, 0, 200, 262144, 131072><<<cb * 32, 256, 0, stream>>>(
            S_b, KT_b, nullptr, rsumB, x12key,
            S_w, KT_w, nullptr, rsumW, x12wvkey,
            cb * 24, rcnt1Buf, rcnt2Buf, b0, cb * 32);
    }

    k_tail<<<BB, 256, 0, stream>>>(x1h, x2h, x12key, x12wvkey,
                                   lwvw, lwvb, lw, lb, out);
}